// Round 6
// baseline (1171.294 us; speedup 1.0000x reference)
//
#include <hip/hip_runtime.h>
#include <math.h>

#define NN 100000
#define NE 1600000
#define IN_DIM 512
#define HID 128
#define N_LAYERS 8
#define NB 98               // ceil(NN/1024)
#define PADMAX 3200000      // NE + 15*NN + slack

typedef __attribute__((ext_vector_type(4))) float f32x4;
typedef __attribute__((ext_vector_type(8))) _Float16 h16x8;
typedef __attribute__((ext_vector_type(2))) _Float16 h16x2;

// ---------------- CSR build (rows padded to multiples of 16) ----------------

__global__ void deg_count_kernel(const int* __restrict__ dst, int* __restrict__ deg) {
    int e = blockIdx.x * blockDim.x + threadIdx.x;
    if (e < NE) atomicAdd(&deg[dst[e]], 1);
}

__global__ void dinv_kernel(const int* __restrict__ deg, float* __restrict__ dinv) {
    int i = blockIdx.x * blockDim.x + threadIdx.x;
    if (i < NN) dinv[i] = rsqrtf((float)(deg[i] + 1));   // +1 self loop
}

__global__ void scan1_kernel(const int* __restrict__ deg, int* __restrict__ bsum) {
    __shared__ int s[16];
    int gi = blockIdx.x * 1024 + threadIdx.x;
    int d = (gi < NN) ? deg[gi] : 0;
    int r = (d + 15) & ~15;                              // padded capacity
    for (int off = 32; off; off >>= 1) r += __shfl_down(r, off, 64);
    if ((threadIdx.x & 63) == 0) s[threadIdx.x >> 6] = r;
    __syncthreads();
    if (threadIdx.x == 0) {
        int t = 0;
        for (int i = 0; i < 16; ++i) t += s[i];
        bsum[blockIdx.x] = t;
    }
}

__global__ void scan2_kernel(const int* __restrict__ bsum, int* __restrict__ boff,
                             int* __restrict__ row_ptr) {
    __shared__ int s[128];
    int tid = threadIdx.x;
    int v = (tid < NB) ? bsum[tid] : 0;
    s[tid] = v;
    __syncthreads();
    for (int off = 1; off < 128; off <<= 1) {
        int t = (tid >= off) ? s[tid - off] : 0;
        __syncthreads();
        s[tid] += t;
        __syncthreads();
    }
    if (tid < NB) boff[tid] = s[tid] - v;   // exclusive
    if (tid == NB - 1) row_ptr[NN] = s[tid];
}

__global__ void scan3_kernel(const int* __restrict__ deg, const int* __restrict__ boff,
                             int* __restrict__ row_ptr, int* __restrict__ cursor) {
    __shared__ int s[1024];
    int tid = threadIdx.x;
    int gi = blockIdx.x * 1024 + tid;
    int d = (gi < NN) ? deg[gi] : 0;
    int v = (d + 15) & ~15;
    s[tid] = v;
    __syncthreads();
    for (int off = 1; off < 1024; off <<= 1) {
        int t = (tid >= off) ? s[tid - off] : 0;
        __syncthreads();
        s[tid] += t;
        __syncthreads();
    }
    if (gi < NN) {
        int o = boff[blockIdx.x] + s[tid] - v;
        row_ptr[gi] = o;
        cursor[gi]  = o;
    }
}

__global__ void pad_kernel(const int* __restrict__ deg, const int* __restrict__ row_ptr,
                           int* __restrict__ col, float* __restrict__ val) {
    int i = blockIdx.x * 256 + threadIdx.x;
    if (i < NN) {
        int d = deg[i];
        int s = row_ptr[i] + d;
        int e = row_ptr[i] + ((d + 15) & ~15);
        for (int p = s; p < e; ++p) { col[p] = 0; val[p] = 0.f; }
    }
}

__global__ void fill_kernel(const int* __restrict__ src, const int* __restrict__ dst,
                            const float* __restrict__ dinv, int* __restrict__ cursor,
                            int* __restrict__ col, float* __restrict__ val) {
    int e = blockIdx.x * blockDim.x + threadIdx.x;
    if (e < NE) {
        int s = src[e], d = dst[e];
        int pos = atomicAdd(&cursor[d], 1);
        col[pos] = s;
        val[pos] = dinv[s] * dinv[d];
    }
}

// ---------------- W prep: fp16 hi/lo split, MFMA B-fragment order ----------------
// B-frag element for (n,kk): B[k = kk*32 + (lane>>4)*8 + j][col = n*16 + (lane&15)]

__global__ void wprep_init_kernel(const float* __restrict__ W,
                                  _Float16* __restrict__ Bhi, _Float16* __restrict__ Blo) {
    int t = blockIdx.x * 256 + threadIdx.x;     // 8 * 16 * 64 = 8192 threads
    if (t >= 8 * 16 * 64) return;
    int lane = t & 63, nkk = t >> 6;
    int n = nkk >> 4, kk = nkk & 15;
    int scol = n * 16 + (lane & 15);
    int sr0 = kk * 32 + (lane >> 4) * 8;
#pragma unroll
    for (int j = 0; j < 8; ++j) {
        float w = W[(size_t)(sr0 + j) * HID + scol];
        _Float16 hi = (_Float16)w;
        _Float16 lo = (_Float16)(w - (float)hi);
        Bhi[(size_t)t * 8 + j] = hi;
        Blo[(size_t)t * 8 + j] = lo;
    }
}

__global__ void wprep_layers_kernel(const float* __restrict__ WL,
                                    _Float16* __restrict__ Bhi, _Float16* __restrict__ Blo) {
    int t = blockIdx.x * 256 + threadIdx.x;     // 8 layers * 8*4*64 = 16384 threads
    if (t >= N_LAYERS * 8 * 4 * 64) return;
    int layer = t >> 11;
    int r = t & 2047;
    int lane = r & 63, nkk = r >> 6;
    int n = nkk >> 2, kk = nkk & 3;
    const float* W = WL + (size_t)layer * HID * HID;
    int scol = n * 16 + (lane & 15);
    int sr0 = kk * 32 + (lane >> 4) * 8;
#pragma unroll
    for (int j = 0; j < 8; ++j) {
        float w = W[(size_t)(sr0 + j) * HID + scol];
        _Float16 hi = (_Float16)w;
        _Float16 lo = (_Float16)(w - (float)hi);
        Bhi[(size_t)t * 8 + j] = hi;
        Blo[(size_t)t * 8 + j] = lo;
    }
}

// ---------------- init projection: fp16(x)[NN][512] @ W[512][128] + b -> fp16 ----------------
// Full-row contiguous LDS staging (fixes HBM channel imbalance of 2KB-strided
// fragment loads). 16 rows/block, 256 thr, 4 waves each computing 2 n-tiles.

__global__ __launch_bounds__(256) void init_mfma_kernel(
    const float* __restrict__ x, const h16x8* __restrict__ Bhi, const h16x8* __restrict__ Blo,
    const float* __restrict__ b, _Float16* __restrict__ cur, _Float16* __restrict__ x0h) {
    __shared__ float xs[16][516];               // pad 4 f32 -> even bank spread
    int t = threadIdx.x;
    int row0 = blockIdx.x * 16;                 // NN % 16 == 0, no tail
    {
        int row = t >> 4, s = t & 15;
        const float4* rsrc = (const float4*)(x + (size_t)(row0 + row) * IN_DIM);
        float4 v[8];
#pragma unroll
        for (int i = 0; i < 8; ++i) v[i] = rsrc[s + i * 16];
#pragma unroll
        for (int i = 0; i < 8; ++i) *(float4*)&xs[row][(s + i * 16) * 4] = v[i];
    }
    __syncthreads();

    int lane = t & 63, wid = t >> 6;
    int rsel = lane & 15, ksel = lane >> 4;
    int n0 = wid * 2;

    f32x4 acc[2];
#pragma unroll
    for (int ni = 0; ni < 2; ++ni) acc[ni] = (f32x4){0.f, 0.f, 0.f, 0.f};

#pragma unroll
    for (int kk = 0; kk < 16; ++kk) {
        const float* ap = &xs[rsel][kk * 32 + ksel * 8];
        float4 a0 = *(const float4*)ap;
        float4 a1 = *(const float4*)(ap + 4);
        h16x8 a;
        a[0] = (_Float16)a0.x; a[1] = (_Float16)a0.y;
        a[2] = (_Float16)a0.z; a[3] = (_Float16)a0.w;
        a[4] = (_Float16)a1.x; a[5] = (_Float16)a1.y;
        a[6] = (_Float16)a1.z; a[7] = (_Float16)a1.w;
#pragma unroll
        for (int ni = 0; ni < 2; ++ni) {
            h16x8 bh = Bhi[((n0 + ni) * 16 + kk) * 64 + lane];
            h16x8 bl = Blo[((n0 + ni) * 16 + kk) * 64 + lane];
            acc[ni] = __builtin_amdgcn_mfma_f32_16x16x32_f16(a, bh, acc[ni], 0, 0, 0);
            acc[ni] = __builtin_amdgcn_mfma_f32_16x16x32_f16(a, bl, acc[ni], 0, 0, 0);
        }
    }

#pragma unroll
    for (int ni = 0; ni < 2; ++ni) {
        int col = (n0 + ni) * 16 + rsel;
        float bias = b[col];
#pragma unroll
        for (int r = 0; r < 4; ++r) {
            int row = row0 + ksel * 4 + r;
            float v = acc[ni][r] + bias;
            _Float16 hv = (_Float16)v;
            cur[(size_t)row * HID + col] = hv;
            x0h[(size_t)row * HID + col] = hv;
        }
    }
}

// ---------------- layer GEMM: cur = relu((1-b)*H + b*(H @ W)) -> fp16 ----------------
// m=1: 4 waves per 64-row block (2x wave count vs m=2), A-frags direct fp16 loads.

__global__ __launch_bounds__(256) void layer_mfma_kernel(
    const _Float16* __restrict__ H,
    const h16x8* __restrict__ Bhi, const h16x8* __restrict__ Blo,
    float beta, _Float16* __restrict__ cur) {
    int lane = threadIdx.x & 63, wid = threadIdx.x >> 6;
    int row0w = blockIdx.x * 64 + wid * 16;
    int rsel = lane & 15, ksel = lane >> 4;

    int arow = row0w + rsel; if (arow >= NN) arow = NN - 1;
    const _Float16* hp = H + (size_t)arow * HID + ksel * 8;
    h16x8 a[4];
#pragma unroll
    for (int kk = 0; kk < 4; ++kk)
        a[kk] = *(const h16x8*)(hp + kk * 32);

    f32x4 acc[8];
#pragma unroll
    for (int n = 0; n < 8; ++n) acc[n] = (f32x4){0.f, 0.f, 0.f, 0.f};

#pragma unroll
    for (int n = 0; n < 8; ++n)
#pragma unroll
        for (int kk = 0; kk < 4; ++kk) {
            h16x8 bh = Bhi[(n * 4 + kk) * 64 + lane];
            h16x8 bl = Blo[(n * 4 + kk) * 64 + lane];
            acc[n] = __builtin_amdgcn_mfma_f32_16x16x32_f16(a[kk], bh, acc[n], 0, 0, 0);
            acc[n] = __builtin_amdgcn_mfma_f32_16x16x32_f16(a[kk], bl, acc[n], 0, 0, 0);
        }

    float ob = 1.0f - beta;
#pragma unroll
    for (int n = 0; n < 8; ++n) {
        int col = n * 16 + rsel;
#pragma unroll
        for (int r = 0; r < 4; ++r) {
            int row = row0w + ksel * 4 + r;
            if (row < NN) {
                size_t o = (size_t)row * HID + col;
                float h = (float)H[o];
                float v = ob * h + beta * acc[n][r];
                v = v > 0.f ? v : 0.f;
                cur[o] = (_Float16)v;
            }
        }
    }
}

// ---------------- sparse aggregation: padded CSR, fp16 gathers, fp16 out ----------------

__global__ __launch_bounds__(256) void agg16_kernel(
    const _Float16* __restrict__ x, const _Float16* __restrict__ x0,
    const int* __restrict__ row_ptr, const int* __restrict__ col,
    const float* __restrict__ val, const float* __restrict__ dinv,
    _Float16* __restrict__ Hout) {
    int node = blockIdx.x * 4 + (threadIdx.x >> 6);
    int lane = threadIdx.x & 63;
    int g = lane >> 4, q = lane & 15;
    const h16x8* x8 = (const h16x8*)x;

    // hoist independent loads ahead of the gather loop
    float di = dinv[node];
    h16x8 sv = x8[(size_t)node * 16 + q];
    h16x8 zv = ((const h16x8*)x0)[(size_t)node * 16 + q];

    float acc[8];
#pragma unroll
    for (int j = 0; j < 8; ++j) acc[j] = 0.f;

    int p1 = row_ptr[node + 1];
#pragma unroll 2
    for (int p = row_ptr[node]; p < p1; p += 16) {
        int4   c4 = *(const int4*)(col + p + 4 * g);
        float4 w4 = *(const float4*)(val + p + 4 * g);
        h16x8 v0 = x8[(size_t)c4.x * 16 + q];
        h16x8 v1 = x8[(size_t)c4.y * 16 + q];
        h16x8 v2 = x8[(size_t)c4.z * 16 + q];
        h16x8 v3 = x8[(size_t)c4.w * 16 + q];
#pragma unroll
        for (int j = 0; j < 8; ++j)
            acc[j] += w4.x * (float)v0[j] + w4.y * (float)v1[j]
                    + w4.z * (float)v2[j] + w4.w * (float)v3[j];
    }

#pragma unroll
    for (int j = 0; j < 8; ++j) {
        acc[j] += __shfl_xor(acc[j], 16, 64);
        acc[j] += __shfl_xor(acc[j], 32, 64);
    }

    if (g == 0) {
        float d2 = di * di;
        h16x8 o16;
#pragma unroll
        for (int j = 0; j < 8; ++j)
            o16[j] = (_Float16)(0.9f * (acc[j] + d2 * (float)sv[j]) + 0.1f * (float)zv[j]);
        ((h16x8*)Hout)[(size_t)node * 16 + q] = o16;
    }
}

// ---------------- final projection ----------------

__global__ __launch_bounds__(256) void final16_kernel(
    const _Float16* __restrict__ x, const float* __restrict__ Wout,
    const float* __restrict__ bout, float* __restrict__ out) {
    int node = blockIdx.x * 4 + (threadIdx.x >> 6);
    int lane = threadIdx.x & 63;
    h16x2 a = ((const h16x2*)x)[(size_t)node * 64 + lane];
    float2 w = ((const float2*)Wout)[lane];
    float v = (float)a[0] * w.x + (float)a[1] * w.y;
#pragma unroll
    for (int off = 32; off; off >>= 1) v += __shfl_down(v, off, 64);
    if (lane == 0) out[node] = v + bout[0];
}

// ---------------- host ----------------

extern "C" void kernel_launch(void* const* d_in, const int* in_sizes, int n_in,
                              void* d_out, int out_size, void* d_ws, size_t ws_size,
                              hipStream_t stream) {
    const float* x_in     = (const float*)d_in[0];
    const int*   ei       = (const int*)d_in[1];
    const float* W_in     = (const float*)d_in[3];
    const float* b_in     = (const float*)d_in[4];
    const float* W_layers = (const float*)d_in[5];
    const float* W_out    = (const float*)d_in[6];
    const float* b_out    = (const float*)d_in[7];
    float* out = (float*)d_out;

    const int* src = ei;
    const int* dst = ei + NE;

    char* ws = (char*)d_ws;
    size_t off = 0;
    auto alloc = [&](size_t bytes) {
        size_t p = off;
        off = (off + bytes + 255) & ~(size_t)255;
        return p;
    };
    int*   deg     = (int*)(ws + alloc((size_t)NN * 4));
    float* dinv    = (float*)(ws + alloc((size_t)NN * 4));
    int*   row_ptr = (int*)(ws + alloc((size_t)(NN + 1) * 4));
    int*   cursor  = (int*)(ws + alloc((size_t)NN * 4));
    int*   bsum    = (int*)(ws + alloc((size_t)NB * 4));
    int*   boff    = (int*)(ws + alloc((size_t)NB * 4));
    int*   col     = (int*)(ws + alloc((size_t)PADMAX * 4));
    float* val     = (float*)(ws + alloc((size_t)PADMAX * 4));
    _Float16* x0h  = (_Float16*)(ws + alloc((size_t)NN * HID * 2));
    _Float16* cur  = (_Float16*)(ws + alloc((size_t)NN * HID * 2));
    _Float16* Hbuf = (_Float16*)(ws + alloc((size_t)NN * HID * 2));
    _Float16* Bhi0 = (_Float16*)(ws + alloc((size_t)IN_DIM * HID * 2));
    _Float16* Blo0 = (_Float16*)(ws + alloc((size_t)IN_DIM * HID * 2));
    _Float16* BhiL = (_Float16*)(ws + alloc((size_t)N_LAYERS * HID * HID * 2));
    _Float16* BloL = (_Float16*)(ws + alloc((size_t)N_LAYERS * HID * HID * 2));

    hipMemsetAsync(deg, 0, (size_t)NN * 4, stream);

    deg_count_kernel<<<NE / 256, 256, 0, stream>>>(dst, deg);
    dinv_kernel<<<(NN + 255) / 256, 256, 0, stream>>>(deg, dinv);
    scan1_kernel<<<NB, 1024, 0, stream>>>(deg, bsum);
    scan2_kernel<<<1, 128, 0, stream>>>(bsum, boff, row_ptr);
    scan3_kernel<<<NB, 1024, 0, stream>>>(deg, boff, row_ptr, cursor);
    pad_kernel<<<(NN + 255) / 256, 256, 0, stream>>>(deg, row_ptr, col, val);
    fill_kernel<<<NE / 256, 256, 0, stream>>>(src, dst, dinv, cursor, col, val);

    wprep_init_kernel<<<32, 256, 0, stream>>>(W_in, Bhi0, Blo0);
    wprep_layers_kernel<<<64, 256, 0, stream>>>(W_layers, BhiL, BloL);

    init_mfma_kernel<<<NN / 16, 256, 0, stream>>>(
        x_in, (const h16x8*)Bhi0, (const h16x8*)Blo0, b_in, cur, x0h);

    for (int l = 0; l < N_LAYERS; ++l) {
        agg16_kernel<<<NN / 4, 256, 0, stream>>>(cur, x0h, row_ptr, col, val, dinv, Hbuf);
        float beta = logf(0.5f / (float)(l + 1) + 1.0f);
        layer_mfma_kernel<<<(NN + 63) / 64, 256, 0, stream>>>(
            Hbuf, (const h16x8*)(BhiL + (size_t)l * HID * HID),
            (const h16x8*)(BloL + (size_t)l * HID * HID), beta, cur);
    }

    final16_kernel<<<NN / 4, 256, 0, stream>>>(cur, W_out, b_out, out);
}

// Round 7
// 1037.107 us; speedup vs baseline: 1.1294x; 1.1294x over previous
//
#include <hip/hip_runtime.h>
#include <math.h>

#define NN 100000
#define NE 1600000
#define IN_DIM 512
#define HID 128
#define N_LAYERS 8
#define NB 98               // ceil(NN/1024)
#define PADMAX 3200000      // NE + 15*NN + slack

typedef __attribute__((ext_vector_type(4))) float f32x4;
typedef __attribute__((ext_vector_type(8))) _Float16 h16x8;
typedef __attribute__((ext_vector_type(2))) _Float16 h16x2;

// ---------------- CSR build (rows padded to multiples of 16) ----------------

__global__ void deg_count_kernel(const int* __restrict__ dst, int* __restrict__ deg) {
    int e = blockIdx.x * blockDim.x + threadIdx.x;
    if (e < NE) atomicAdd(&deg[dst[e]], 1);
}

__global__ void dinv_kernel(const int* __restrict__ deg, float* __restrict__ dinv) {
    int i = blockIdx.x * blockDim.x + threadIdx.x;
    if (i < NN) dinv[i] = rsqrtf((float)(deg[i] + 1));   // +1 self loop
}

__global__ void scan1_kernel(const int* __restrict__ deg, int* __restrict__ bsum) {
    __shared__ int s[16];
    int gi = blockIdx.x * 1024 + threadIdx.x;
    int d = (gi < NN) ? deg[gi] : 0;
    int r = (d + 15) & ~15;                              // padded capacity
    for (int off = 32; off; off >>= 1) r += __shfl_down(r, off, 64);
    if ((threadIdx.x & 63) == 0) s[threadIdx.x >> 6] = r;
    __syncthreads();
    if (threadIdx.x == 0) {
        int t = 0;
        for (int i = 0; i < 16; ++i) t += s[i];
        bsum[blockIdx.x] = t;
    }
}

__global__ void scan2_kernel(const int* __restrict__ bsum, int* __restrict__ boff,
                             int* __restrict__ row_ptr) {
    __shared__ int s[128];
    int tid = threadIdx.x;
    int v = (tid < NB) ? bsum[tid] : 0;
    s[tid] = v;
    __syncthreads();
    for (int off = 1; off < 128; off <<= 1) {
        int t = (tid >= off) ? s[tid - off] : 0;
        __syncthreads();
        s[tid] += t;
        __syncthreads();
    }
    if (tid < NB) boff[tid] = s[tid] - v;   // exclusive
    if (tid == NB - 1) row_ptr[NN] = s[tid];
}

__global__ void scan3_kernel(const int* __restrict__ deg, const int* __restrict__ boff,
                             int* __restrict__ row_ptr, int* __restrict__ cursor) {
    __shared__ int s[1024];
    int tid = threadIdx.x;
    int gi = blockIdx.x * 1024 + tid;
    int d = (gi < NN) ? deg[gi] : 0;
    int v = (d + 15) & ~15;
    s[tid] = v;
    __syncthreads();
    for (int off = 1; off < 1024; off <<= 1) {
        int t = (tid >= off) ? s[tid - off] : 0;
        __syncthreads();
        s[tid] += t;
        __syncthreads();
    }
    if (gi < NN) {
        int o = boff[blockIdx.x] + s[tid] - v;
        row_ptr[gi] = o;
        cursor[gi]  = o;
    }
}

__global__ void pad_kernel(const int* __restrict__ deg, const int* __restrict__ row_ptr,
                           int* __restrict__ col, float* __restrict__ val) {
    int i = blockIdx.x * 256 + threadIdx.x;
    if (i < NN) {
        int d = deg[i];
        int s = row_ptr[i] + d;
        int e = row_ptr[i] + ((d + 15) & ~15);
        for (int p = s; p < e; ++p) { col[p] = 0; val[p] = 0.f; }
    }
}

__global__ void fill_kernel(const int* __restrict__ src, const int* __restrict__ dst,
                            const float* __restrict__ dinv, int* __restrict__ cursor,
                            int* __restrict__ col, float* __restrict__ val) {
    int e = blockIdx.x * blockDim.x + threadIdx.x;
    if (e < NE) {
        int s = src[e], d = dst[e];
        int pos = atomicAdd(&cursor[d], 1);
        col[pos] = s;
        val[pos] = dinv[s] * dinv[d];
    }
}

// ---------------- W prep: fp16 hi/lo split, MFMA B-fragment order ----------------
// B-frag element for (n,kk): B[k = kk*32 + (lane>>4)*8 + j][col = n*16 + (lane&15)]

__global__ void wprep_init_kernel(const float* __restrict__ W,
                                  _Float16* __restrict__ Bhi, _Float16* __restrict__ Blo) {
    int t = blockIdx.x * 256 + threadIdx.x;     // 8 * 16 * 64 = 8192 threads
    if (t >= 8 * 16 * 64) return;
    int lane = t & 63, nkk = t >> 6;
    int n = nkk >> 4, kk = nkk & 15;
    int scol = n * 16 + (lane & 15);
    int sr0 = kk * 32 + (lane >> 4) * 8;
#pragma unroll
    for (int j = 0; j < 8; ++j) {
        float w = W[(size_t)(sr0 + j) * HID + scol];
        _Float16 hi = (_Float16)w;
        _Float16 lo = (_Float16)(w - (float)hi);
        Bhi[(size_t)t * 8 + j] = hi;
        Blo[(size_t)t * 8 + j] = lo;
    }
}

__global__ void wprep_layers_kernel(const float* __restrict__ WL,
                                    _Float16* __restrict__ Bhi, _Float16* __restrict__ Blo) {
    int t = blockIdx.x * 256 + threadIdx.x;     // 8 layers * 8*4*64 = 16384 threads
    if (t >= N_LAYERS * 8 * 4 * 64) return;
    int layer = t >> 11;
    int r = t & 2047;
    int lane = r & 63, nkk = r >> 6;
    int n = nkk >> 2, kk = nkk & 3;
    const float* W = WL + (size_t)layer * HID * HID;
    int scol = n * 16 + (lane & 15);
    int sr0 = kk * 32 + (lane >> 4) * 8;
#pragma unroll
    for (int j = 0; j < 8; ++j) {
        float w = W[(size_t)(sr0 + j) * HID + scol];
        _Float16 hi = (_Float16)w;
        _Float16 lo = (_Float16)(w - (float)hi);
        Bhi[(size_t)t * 8 + j] = hi;
        Blo[(size_t)t * 8 + j] = lo;
    }
}

// ---------------- init projection: fp16(x)[NN][512] @ W[512][128] + b -> fp16 ----------------
// 64 rows/block, 512 thr. Staging reads the block's 128KB x-span FULLY LINEARLY
// (all HBM channels each instant), cvt fp32->fp16, XOR-swizzled LDS tile
// (blk^=row&7 -> 2-way bank conflicts = free). 8 waves x 1 n-tile x 4 m-tiles:
// B-fragment L2 traffic /4 vs per-wave-2-ntile layout.

__device__ inline int xsw(int row, int blk) {      // fp16 offset in [64][512] tile
    return row * 512 + ((blk ^ (row & 7)) << 3);
}

__global__ __launch_bounds__(512) void init_mfma_kernel(
    const float* __restrict__ x, const h16x8* __restrict__ Bhi, const h16x8* __restrict__ Blo,
    const float* __restrict__ b, _Float16* __restrict__ cur, _Float16* __restrict__ x0h) {
    __shared__ _Float16 xs[64 * 512];           // 64KB, swizzled blocks of 8 fp16
    int t = threadIdx.x;
    int row0 = blockIdx.x * 64;

#pragma unroll
    for (int i = 0; i < 8; ++i) {               // linear 32B chunks: c = t + 512*i
        int c = t + 512 * i;
        int row = c >> 6, blk = c & 63;
        int grow = row0 + row; if (grow >= NN) grow = NN - 1;
        const float* p = x + (size_t)grow * IN_DIM + blk * 8;
        float4 v0 = *(const float4*)p;
        float4 v1 = *(const float4*)(p + 4);
        h16x8 h;
        h[0] = (_Float16)v0.x; h[1] = (_Float16)v0.y;
        h[2] = (_Float16)v0.z; h[3] = (_Float16)v0.w;
        h[4] = (_Float16)v1.x; h[5] = (_Float16)v1.y;
        h[6] = (_Float16)v1.z; h[7] = (_Float16)v1.w;
        *(h16x8*)&xs[xsw(row, blk)] = h;
    }
    __syncthreads();

    int lane = t & 63, wid = t >> 6;            // wave = n-tile
    int rsel = lane & 15, ksel = lane >> 4;

    f32x4 acc[4];
#pragma unroll
    for (int m = 0; m < 4; ++m) acc[m] = (f32x4){0.f, 0.f, 0.f, 0.f};

#pragma unroll
    for (int kk = 0; kk < 16; ++kk) {
        h16x8 bh = Bhi[(wid * 16 + kk) * 64 + lane];
        h16x8 bl = Blo[(wid * 16 + kk) * 64 + lane];
#pragma unroll
        for (int m = 0; m < 4; ++m) {
            h16x8 a = *(const h16x8*)&xs[xsw(m * 16 + rsel, kk * 4 + ksel)];
            acc[m] = __builtin_amdgcn_mfma_f32_16x16x32_f16(a, bh, acc[m], 0, 0, 0);
            acc[m] = __builtin_amdgcn_mfma_f32_16x16x32_f16(a, bl, acc[m], 0, 0, 0);
        }
    }

    int col = wid * 16 + rsel;
    float bias = b[col];
#pragma unroll
    for (int m = 0; m < 4; ++m) {
#pragma unroll
        for (int r = 0; r < 4; ++r) {
            int row = row0 + m * 16 + ksel * 4 + r;
            if (row < NN) {
                float v = acc[m][r] + bias;
                _Float16 hv = (_Float16)v;
                cur[(size_t)row * HID + col] = hv;
                x0h[(size_t)row * HID + col] = hv;
            }
        }
    }
}

// ---------------- fused layer: agg -> LDS -> MFMA -> relu/residual -> out ----------------
// 64 nodes/block, 8 waves. B-frags preloaded to regs BEFORE agg (L2 latency
// hidden under gathers). h tile in XOR-swizzled LDS [64][128] fp16 (16KB).

__device__ inline int hsw(int row, int blk) {      // fp16 offset in [64][128] tile
    return row * 128 + ((blk ^ (row & 7)) << 3);
}

__global__ __launch_bounds__(512) void fused_layer_kernel(
    const _Float16* __restrict__ x, const _Float16* __restrict__ x0,
    const int* __restrict__ row_ptr, const int* __restrict__ col,
    const float* __restrict__ val, const float* __restrict__ dinv,
    const h16x8* __restrict__ Bhi, const h16x8* __restrict__ Blo,
    float beta, _Float16* __restrict__ out) {
    __shared__ _Float16 hs[64 * 128];
    int t = threadIdx.x;
    int lane = t & 63, wid = t >> 6;
    int node0 = blockIdx.x * 64;

    // preload this wave's n-tile B fragments (independent of agg)
    h16x8 bh[4], bl[4];
#pragma unroll
    for (int kk = 0; kk < 4; ++kk) {
        bh[kk] = Bhi[(wid * 4 + kk) * 64 + lane];
        bl[kk] = Blo[(wid * 4 + kk) * 64 + lane];
    }

    // ---- agg phase: wave handles 8 nodes ----
    int g = lane >> 4, q = lane & 15;
    const h16x8* x8 = (const h16x8*)x;
    for (int i = 0; i < 8; ++i) {
        int lrow = wid * 8 + i;
        int node = node0 + lrow;
        if (node < NN) {
            float di = dinv[node];
            h16x8 sv = x8[(size_t)node * 16 + q];
            h16x8 zv = ((const h16x8*)x0)[(size_t)node * 16 + q];
            float acc[8];
#pragma unroll
            for (int j = 0; j < 8; ++j) acc[j] = 0.f;
            int p1 = row_ptr[node + 1];
            for (int p = row_ptr[node]; p < p1; p += 16) {
                int4   c4 = *(const int4*)(col + p + 4 * g);
                float4 w4 = *(const float4*)(val + p + 4 * g);
                h16x8 v0 = x8[(size_t)c4.x * 16 + q];
                h16x8 v1 = x8[(size_t)c4.y * 16 + q];
                h16x8 v2 = x8[(size_t)c4.z * 16 + q];
                h16x8 v3 = x8[(size_t)c4.w * 16 + q];
#pragma unroll
                for (int j = 0; j < 8; ++j)
                    acc[j] += w4.x * (float)v0[j] + w4.y * (float)v1[j]
                            + w4.z * (float)v2[j] + w4.w * (float)v3[j];
            }
#pragma unroll
            for (int j = 0; j < 8; ++j) {
                acc[j] += __shfl_xor(acc[j], 16, 64);
                acc[j] += __shfl_xor(acc[j], 32, 64);
            }
            if (g == 0) {
                float d2 = di * di;
                h16x8 o16;
#pragma unroll
                for (int j = 0; j < 8; ++j)
                    o16[j] = (_Float16)(0.9f * (acc[j] + d2 * (float)sv[j]) + 0.1f * (float)zv[j]);
                *(h16x8*)&hs[hsw(lrow, q)] = o16;
            }
        } else if (g == 0) {
            h16x8 z;
#pragma unroll
            for (int j = 0; j < 8; ++j) z[j] = (_Float16)0.f;
            *(h16x8*)&hs[hsw(lrow, q)] = z;
        }
    }
    __syncthreads();

    // ---- MFMA phase: wave = n-tile wid, 4 m-tiles ----
    int rsel = lane & 15, ksel = lane >> 4;
    f32x4 acc[4];
#pragma unroll
    for (int m = 0; m < 4; ++m) acc[m] = (f32x4){0.f, 0.f, 0.f, 0.f};

#pragma unroll
    for (int m = 0; m < 4; ++m)
#pragma unroll
        for (int kk = 0; kk < 4; ++kk) {
            h16x8 a = *(const h16x8*)&hs[hsw(m * 16 + rsel, kk * 4 + ksel)];
            acc[m] = __builtin_amdgcn_mfma_f32_16x16x32_f16(a, bh[kk], acc[m], 0, 0, 0);
            acc[m] = __builtin_amdgcn_mfma_f32_16x16x32_f16(a, bl[kk], acc[m], 0, 0, 0);
        }

    float ob = 1.0f - beta;
    int colw = wid * 16 + rsel;
#pragma unroll
    for (int m = 0; m < 4; ++m) {
#pragma unroll
        for (int r = 0; r < 4; ++r) {
            int lr = m * 16 + ksel * 4 + r;
            int row = node0 + lr;
            if (row < NN) {
                float h = (float)hs[lr * 128 + (((colw >> 3) ^ (lr & 7)) << 3) + (colw & 7)];
                float v = ob * h + beta * acc[m][r];
                v = v > 0.f ? v : 0.f;
                out[(size_t)row * HID + colw] = (_Float16)v;
            }
        }
    }
}

// ---------------- final projection ----------------

__global__ __launch_bounds__(256) void final16_kernel(
    const _Float16* __restrict__ x, const float* __restrict__ Wout,
    const float* __restrict__ bout, float* __restrict__ out) {
    int node = blockIdx.x * 4 + (threadIdx.x >> 6);
    int lane = threadIdx.x & 63;
    h16x2 a = ((const h16x2*)x)[(size_t)node * 64 + lane];
    float2 w = ((const float2*)Wout)[lane];
    float v = (float)a[0] * w.x + (float)a[1] * w.y;
#pragma unroll
    for (int off = 32; off; off >>= 1) v += __shfl_down(v, off, 64);
    if (lane == 0) out[node] = v + bout[0];
}

// ---------------- host ----------------

extern "C" void kernel_launch(void* const* d_in, const int* in_sizes, int n_in,
                              void* d_out, int out_size, void* d_ws, size_t ws_size,
                              hipStream_t stream) {
    const float* x_in     = (const float*)d_in[0];
    const int*   ei       = (const int*)d_in[1];
    const float* W_in     = (const float*)d_in[3];
    const float* b_in     = (const float*)d_in[4];
    const float* W_layers = (const float*)d_in[5];
    const float* W_out    = (const float*)d_in[6];
    const float* b_out    = (const float*)d_in[7];
    float* out = (float*)d_out;

    const int* src = ei;
    const int* dst = ei + NE;

    char* ws = (char*)d_ws;
    size_t off = 0;
    auto alloc = [&](size_t bytes) {
        size_t p = off;
        off = (off + bytes + 255) & ~(size_t)255;
        return p;
    };
    int*   deg     = (int*)(ws + alloc((size_t)NN * 4));
    float* dinv    = (float*)(ws + alloc((size_t)NN * 4));
    int*   row_ptr = (int*)(ws + alloc((size_t)(NN + 1) * 4));
    int*   cursor  = (int*)(ws + alloc((size_t)NN * 4));
    int*   bsum    = (int*)(ws + alloc((size_t)NB * 4));
    int*   boff    = (int*)(ws + alloc((size_t)NB * 4));
    int*   col     = (int*)(ws + alloc((size_t)PADMAX * 4));
    float* val     = (float*)(ws + alloc((size_t)PADMAX * 4));
    _Float16* x0h  = (_Float16*)(ws + alloc((size_t)NN * HID * 2));
    _Float16* bufA = (_Float16*)(ws + alloc((size_t)NN * HID * 2));
    _Float16* bufB = (_Float16*)(ws + alloc((size_t)NN * HID * 2));
    _Float16* Bhi0 = (_Float16*)(ws + alloc((size_t)IN_DIM * HID * 2));
    _Float16* Blo0 = (_Float16*)(ws + alloc((size_t)IN_DIM * HID * 2));
    _Float16* BhiL = (_Float16*)(ws + alloc((size_t)N_LAYERS * HID * HID * 2));
    _Float16* BloL = (_Float16*)(ws + alloc((size_t)N_LAYERS * HID * HID * 2));

    hipMemsetAsync(deg, 0, (size_t)NN * 4, stream);

    deg_count_kernel<<<NE / 256, 256, 0, stream>>>(dst, deg);
    dinv_kernel<<<(NN + 255) / 256, 256, 0, stream>>>(deg, dinv);
    scan1_kernel<<<NB, 1024, 0, stream>>>(deg, bsum);
    scan2_kernel<<<1, 128, 0, stream>>>(bsum, boff, row_ptr);
    scan3_kernel<<<NB, 1024, 0, stream>>>(deg, boff, row_ptr, cursor);
    pad_kernel<<<(NN + 255) / 256, 256, 0, stream>>>(deg, row_ptr, col, val);
    fill_kernel<<<NE / 256, 256, 0, stream>>>(src, dst, dinv, cursor, col, val);

    wprep_init_kernel<<<32, 256, 0, stream>>>(W_in, Bhi0, Blo0);
    wprep_layers_kernel<<<64, 256, 0, stream>>>(W_layers, BhiL, BloL);

    init_mfma_kernel<<<(NN + 63) / 64, 512, 0, stream>>>(
        x_in, (const h16x8*)Bhi0, (const h16x8*)Blo0, b_in, bufA, x0h);

    _Float16* cur = bufA;
    _Float16* nxt = bufB;
    for (int l = 0; l < N_LAYERS; ++l) {
        float beta = logf(0.5f / (float)(l + 1) + 1.0f);
        fused_layer_kernel<<<(NN + 63) / 64, 512, 0, stream>>>(
            cur, x0h, row_ptr, col, val, dinv,
            (const h16x8*)(BhiL + (size_t)l * HID * HID),
            (const h16x8*)(BloL + (size_t)l * HID * HID), beta, nxt);
        _Float16* tmp = cur; cur = nxt; nxt = tmp;
    }

    final16_kernel<<<NN / 4, 256, 0, stream>>>(cur, W_out, b_out, out);
}